// Round 10
// baseline (131.228 us; speedup 1.0000x reference)
//
#include <hip/hip_runtime.h>

// NonLocalBlock, B=4, C=64, H=W=64, N=4096, Ch=32.  MFMA f16, resident-frag i-loop.
//
// Index algebra (verified rounds 1-9):
//  x1[b,i,k] = conv1_flat[b][i*32+k]   (raw reshape; conv1 [ch][hw] buffer IS x1 flat)
//  x2[b,k,j] = conv2 natural [k][j]
//  y3[b,j,c] = conv3_flat[b][j*32+c]
//  attn[b,i,j] = sum_k x1*x2 ; softmax over BATCH axis (4 elems, per (i,j))
//  O[b,i,c] = sum_j attn*y3 ;  y2[b,ch,hw] = O_flat[b][ch*4096+hw] -> conv4
//
// MFMA f16 16x16x32 (HW-verified r2-r9):
//  A: A[m=lane&15][k=(lane>>4)*8+e]   B: B[k=(lane>>4)*8+e][n=lane&15]
//  C/D: row=(lane>>4)*4+reg, col=lane&15;  A-frag of M == B-frag of M^T.
// Stage 1 computes S^T with PERMUTED X2 rows (tile jh row m' -> j=(m'>>2)*8+(m'&3)+jh*4)
// so lane (q,m) ends holding exactly P[i=m][k=q*8+e] = stage-2 B-frag. No transpose.
// X2f/Y3f fragment-order buffers -> attn loads are lane*16B contiguous:
//  X2f h8-index: ((b*128 + jt)*2 + jh)*64 + lane  (value: x2[b][k=q*8+e][jt*32+perm(m,jh)])
//  Y3f h8-index: ((b*128 + jt)*2 + ch)*64 + lane  (value: y3[b][jt*32+q*8+e][ch*16+m])
// X1 carries log2e so softmax is raw exp2 (|s*log2e| < ~50, safe in f32).
// r10: attn keeps j-frags RESIDENT in registers and loops 8 i-tiles per block
//  (traffic 512->128 MB); dbuf LDS cross-wave reduce (1 barrier/iter); bx1 prefetch.
//
// ws: X1h 1MB @0 | X2f 1MB @1M | Y3f 1MB @2M | OPh 32MB @3M (32 f16 slices)

typedef _Float16 half8 __attribute__((ext_vector_type(8)));
typedef _Float16 half4 __attribute__((ext_vector_type(4)));
typedef float f32x4 __attribute__((ext_vector_type(4)));

#define N_PIX 4096
#define NB    4
#define JS    32
#define IT    8      // i-tiles per attn block
#define LOG2E 1.44269504088896f

// grid (256, 3): bx = b(2b) | chunk(4b, 256 hw) | og(2b, 8 o).  LDS weights.
__global__ __launch_bounds__(256) void convs_kernel(
    const float* __restrict__ x,
    const float* __restrict__ w1, const float* __restrict__ b1,
    const float* __restrict__ w2, const float* __restrict__ b2,
    const float* __restrict__ w3, const float* __restrict__ b3,
    _Float16* __restrict__ X1h, _Float16* __restrict__ X2f, _Float16* __restrict__ Y3f)
{
    const int t = blockIdx.y;
    const float* __restrict__ w  = (t == 0) ? w1 : ((t == 1) ? w2 : w3);
    const float* __restrict__ bb = (t == 0) ? b1 : ((t == 1) ? b2 : b3);

    __shared__ float sw[8][64];            // this block's 8 o rows (2 KB)
    __shared__ float sbias[8];
    __shared__ _Float16 sbuf[2048];        // union: t1 [256 j][8 k] | t2 [8 o][32 c][8 jl]

    const int tid   = threadIdx.x;
    const int b     = blockIdx.x >> 6;
    const int chunk = (blockIdx.x >> 2) & 15;
    const int og    = blockIdx.x & 3;
    const int o0    = og * 8;
    const int hw    = chunk * 256 + tid;

    for (int e = tid; e < 8 * 64; e += 256)
        sw[e >> 6][e & 63] = w[(o0 + (e >> 6)) * 64 + (e & 63)];
    if (tid < 8) sbias[tid] = bb[o0 + tid];
    __syncthreads();

    float xi[64];
    const float* xb = x + b * 64 * N_PIX + hw;
    #pragma unroll
    for (int c = 0; c < 64; c++) xi[c] = xb[c * N_PIX];

    float acc[8];
    #pragma unroll
    for (int oo = 0; oo < 8; oo++) {
        float a0 = sbias[oo], a1 = 0.f, a2 = 0.f, a3 = 0.f;
        #pragma unroll
        for (int c = 0; c < 64; c += 4) {
            a0 += xi[c + 0] * sw[oo][c + 0];
            a1 += xi[c + 1] * sw[oo][c + 1];
            a2 += xi[c + 2] * sw[oo][c + 2];
            a3 += xi[c + 3] * sw[oo][c + 3];
        }
        acc[oo] = (a0 + a1) + (a2 + a3);
    }

    if (t == 0) {
        // X1h flat [o][hw] (== x1 flat [i*32+k]); fold log2e for exp2 softmax
        #pragma unroll
        for (int oo = 0; oo < 8; oo++)
            X1h[b * 131072 + (o0 + oo) * N_PIX + hw] = (_Float16)(acc[oo] * LOG2E);
    } else if (t == 1) {
        // block's k-range o0..o0+7 = exactly q=og octet of the frag; sbuf[j_loc][e]
        #pragma unroll
        for (int oo = 0; oo < 8; oo++)
            sbuf[tid * 8 + oo] = (_Float16)acc[oo];
        __syncthreads();
        const int m    = tid & 15;
        const int jh   = (tid >> 4) & 1;
        const int jt_l = (tid >> 5) & 7;                   // 8 j-tiles per 256 hw
        const int jl   = jt_l * 32 + ((m >> 2) * 8) + (m & 3) + jh * 4;  // perm row
        half8 v = *(half8*)&sbuf[jl * 8];
        *(half8*)&X2f[(((b * 128 + chunk * 8 + jt_l) * 2 + jh) * 64 + og * 16 + m) * 8] = v;
    } else {
        // y3 elem acc[oo]: o = o0+oo, j = o*128 + (hw>>5), c = hw&31.
        // jt = (o0+oo)*4 + (chunk>>2); within-tile j&31: q = chunk&3, e = jl.
        const int c  = tid & 31;
        const int jl = tid >> 5;                           // 0..7
        #pragma unroll
        for (int oo = 0; oo < 8; oo++)
            sbuf[(oo * 32 + c) * 8 + jl] = (_Float16)acc[oo];
        __syncthreads();
        const int m  = tid & 15;
        const int ch = (tid >> 4) & 1;
        const int oo = (tid >> 5) & 7;
        half8 v = *(half8*)&sbuf[(oo * 32 + ch * 16 + m) * 8];
        const int jt = (o0 + oo) * 4 + (chunk >> 2);
        *(half8*)&Y3f[(((b * 128 + jt) * 2 + ch) * 64 + (chunk & 3) * 16 + m) * 8] = v;
    }
}

// grid (32, 32): bx = i-group (8 i-tiles), by = js. Wave wv owns jt = js*4+wv, with
// its X2f/Y3f fragments RESIDENT in registers across the 8 i-tile iterations.
__global__ __launch_bounds__(256) void attn_kernel(
    const _Float16* __restrict__ X1h, const _Float16* __restrict__ X2f,
    const _Float16* __restrict__ Y3f, _Float16* __restrict__ OPh)
{
    __shared__ _Float16 sRedH[2][4 * 64 * 36];   // 2 x 18.4 KB dbuf, stride 36

    const int tid  = threadIdx.x;
    const int wv   = tid >> 6;
    const int lane = tid & 63;
    const int m    = lane & 15;
    const int q    = lane >> 4;
    const int ig   = blockIdx.x;             // i-group: i in [ig*128, ig*128+128)
    const int js   = blockIdx.y;
    const int jg   = js * 4 + wv;            // this wave's single j-tile

    // resident j-fragments (loaded once, reused by all 8 i-tiles)
    half8 ax2[NB][2], ay3[NB][2];
    #pragma unroll
    for (int b = 0; b < NB; b++) {
        #pragma unroll
        for (int jh = 0; jh < 2; jh++)
            ax2[b][jh] = *(const half8*)&X2f[(((b * 128 + jg) * 2 + jh) * 64 + lane) * 8];
        #pragma unroll
        for (int ch = 0; ch < 2; ch++)
            ay3[b][ch] = *(const half8*)&Y3f[(((b * 128 + jg) * 2 + ch) * 64 + lane) * 8];
    }

    // prefetch first i-tile's x1 frags
    half8 nbx1[NB];
    #pragma unroll
    for (int b = 0; b < NB; b++)
        nbx1[b] = *(const half8*)&X1h[b * 131072 + (ig * 128 + m) * 32 + q * 8];

    #pragma unroll 2
    for (int it = 0; it < IT; it++) {
        half8 bx1[NB];
        #pragma unroll
        for (int b = 0; b < NB; b++) bx1[b] = nbx1[b];
        if (it + 1 < IT) {
            #pragma unroll
            for (int b = 0; b < NB; b++)
                nbx1[b] = *(const half8*)&X1h[b * 131072 + (ig * 128 + (it + 1) * 16 + m) * 32 + q * 8];
        }

        // stage 1: S^T (logits pre-scaled by log2e)
        f32x4 sT[NB][2];
        #pragma unroll
        for (int b = 0; b < NB; b++)
            #pragma unroll
            for (int jh = 0; jh < 2; jh++)
                sT[b][jh] = __builtin_amdgcn_mfma_f32_16x16x32_f16(
                    ax2[b][jh], bx1[b], (f32x4){0.f, 0.f, 0.f, 0.f}, 0, 0, 0);

        // batch-softmax via raw exp2, pack stage-2 B-frag in-lane
        half8 pf[NB];
        #pragma unroll
        for (int jh = 0; jh < 2; jh++)
            #pragma unroll
            for (int r = 0; r < 4; r++) {
                float e0 = exp2f(sT[0][jh][r]);
                float e1 = exp2f(sT[1][jh][r]);
                float e2 = exp2f(sT[2][jh][r]);
                float e3 = exp2f(sT[3][jh][r]);
                float rs = __builtin_amdgcn_rcpf(e0 + e1 + e2 + e3);
                pf[0][jh * 4 + r] = (_Float16)(e0 * rs);
                pf[1][jh * 4 + r] = (_Float16)(e1 * rs);
                pf[2][jh * 4 + r] = (_Float16)(e2 * rs);
                pf[3][jh * 4 + r] = (_Float16)(e3 * rs);
            }

        // stage 2: O^T = Y3^T x P^T  (partial over this wave's 32 j)
        f32x4 oaccT[NB][2];
        #pragma unroll
        for (int b = 0; b < NB; b++)
            #pragma unroll
            for (int ch = 0; ch < 2; ch++)
                oaccT[b][ch] = __builtin_amdgcn_mfma_f32_16x16x32_f16(
                    ay3[b][ch], pf[b], (f32x4){0.f, 0.f, 0.f, 0.f}, 0, 0, 0);

        // cross-wave reduction (4 waves = 4 j-tiles of same i-tile), dbuf LDS:
        // 1 barrier/iter; writing buf[p^1] next iter can't race pending reads of buf[p]
        // because those reads precede the next barrier in every wave's program order.
        const int p = it & 1;
        #pragma unroll
        for (int b = 0; b < NB; b++)
            #pragma unroll
            for (int ch = 0; ch < 2; ch++) {
                half4 h;
                #pragma unroll
                for (int r = 0; r < 4; r++) h[r] = (_Float16)oaccT[b][ch][r];
                *(half4*)&sRedH[p][(wv * 64 + lane) * 36 + b * 8 + ch * 4] = h;
            }
        __syncthreads();

        const int i0 = ig * 128 + it * 16;
        #pragma unroll
        for (int ch = 0; ch < 2; ch++) {
            half4 h0 = *(half4*)&sRedH[p][(0 * 64 + lane) * 36 + wv * 8 + ch * 4];
            half4 h1 = *(half4*)&sRedH[p][(1 * 64 + lane) * 36 + wv * 8 + ch * 4];
            half4 h2 = *(half4*)&sRedH[p][(2 * 64 + lane) * 36 + wv * 8 + ch * 4];
            half4 h3 = *(half4*)&sRedH[p][(3 * 64 + lane) * 36 + wv * 8 + ch * 4];
            half4 v;
            #pragma unroll
            for (int r = 0; r < 4; r++)
                v[r] = (_Float16)(((float)h0[r] + (float)h1[r]) + ((float)h2[r] + (float)h3[r]));
            // wave wv writes batch b=wv for this i-tile
            *(half4*)&OPh[js * 524288 + (wv * 4096 + i0 + m) * 32 + ch * 16 + q * 4] = v;
        }
    }
}

// grid 256: bx = b(2b) | chunk(6b, 64 hw).  Sum 32 f16 OPh slices + conv4, fused.
__global__ __launch_bounds__(256) void reduce_out_kernel(
    const _Float16* __restrict__ OPh, const float* __restrict__ w4,
    const float* __restrict__ b4, float* __restrict__ out)
{
    __shared__ float sY[32 * 72];            // [ch][hw_l], pad 72 (16B-aligned, no conflicts)
    __shared__ float sw[64 * 32];            // all of w4 (8 KB)
    __shared__ float sbias[64];

    const int tid = threadIdx.x;
    for (int e = tid; e < 64 * 32; e += 256) sw[e] = w4[e];
    if (tid < 64) sbias[tid] = b4[tid];

    const int b   = blockIdx.x >> 6;
    const int hw0 = (blockIdx.x & 63) * 64;

    // phase 1: reduce 32 partial slices (coalesced half8 loads, 32 independent)
    const int ch    = tid >> 3;
    const int piece = tid & 7;
    {
        float acc[8] = {};
        const _Float16* base = OPh + b * 131072 + ch * 4096 + hw0 + piece * 8;
        #pragma unroll
        for (int p = 0; p < JS; p++) {
            half8 v = *(const half8*)&base[p * 524288];
            #pragma unroll
            for (int e = 0; e < 8; e++) acc[e] += (float)v[e];
        }
        *(f32x4*)&sY[ch * 72 + piece * 8]     = (f32x4){acc[0], acc[1], acc[2], acc[3]};
        *(f32x4*)&sY[ch * 72 + piece * 8 + 4] = (f32x4){acc[4], acc[5], acc[6], acc[7]};
    }
    __syncthreads();

    // phase 2: conv4.  y2[c] reads are conflict-free (consecutive hw_l per lane).
    const int hw_l = tid & 63;
    const int og   = tid >> 6;               // 0..3 -> 16-o quarters

    float y2[32];
    #pragma unroll
    for (int c = 0; c < 32; c++) y2[c] = sY[c * 72 + hw_l];

    float* obp = out + b * 64 * N_PIX + hw0 + hw_l;
    #pragma unroll
    for (int oo = 0; oo < 16; oo++) {
        const int o = og * 16 + oo;
        float a0 = sbias[o], a1 = 0.f, a2 = 0.f, a3 = 0.f;
        #pragma unroll
        for (int c = 0; c < 32; c += 4) {
            a0 += y2[c + 0] * sw[o * 32 + c + 0];
            a1 += y2[c + 1] * sw[o * 32 + c + 1];
            a2 += y2[c + 2] * sw[o * 32 + c + 2];
            a3 += y2[c + 3] * sw[o * 32 + c + 3];
        }
        obp[o * N_PIX] = (a0 + a1) + (a2 + a3);
    }
}

extern "C" void kernel_launch(void* const* d_in, const int* in_sizes, int n_in,
                              void* d_out, int out_size, void* d_ws, size_t ws_size,
                              hipStream_t stream) {
    const float* x  = (const float*)d_in[0];
    const float* w1 = (const float*)d_in[1];
    const float* b1 = (const float*)d_in[2];
    const float* w2 = (const float*)d_in[3];
    const float* b2 = (const float*)d_in[4];
    const float* w3 = (const float*)d_in[5];
    const float* b3 = (const float*)d_in[6];
    const float* w4 = (const float*)d_in[7];
    const float* b4 = (const float*)d_in[8];

    char* wsb = (char*)d_ws;
    _Float16* X1h = (_Float16*)(wsb);
    _Float16* X2f = (_Float16*)(wsb + (1 << 20));
    _Float16* Y3f = (_Float16*)(wsb + (2 << 20));
    _Float16* OPh = (_Float16*)(wsb + (3 << 20));    // JS x 1MB f16 = 32 MB
    float*    out = (float*)d_out;

    dim3 g1(256, 3);
    convs_kernel<<<g1, 256, 0, stream>>>(x, w1, b1, w2, b2, w3, b3, X1h, X2f, Y3f);
    dim3 g2(32, JS);
    attn_kernel<<<g2, 256, 0, stream>>>(X1h, X2f, Y3f, OPh);
    reduce_out_kernel<<<256, 256, 0, stream>>>(OPh, w4, b4, out);
}

// Round 11
// 127.512 us; speedup vs baseline: 1.0291x; 1.0291x over previous
//
#include <hip/hip_runtime.h>

// NonLocalBlock, B=4, C=64, H=W=64, N=4096, Ch=32.  MFMA f16, occupancy-first.
// r11 = exact revert to r8 (best measured: 127.6 us). r9 (merged epilogue @1 block/CU)
// and r10 (resident-frag i-loop @1024 blocks) were both neutral-to-worse; the total is
// dominated by the harness's fixed ~95us ws-poison fill, and r8's high-occupancy
// attn (JS=16, 4096 blocks, ~80 VGPR) is the measured optimum for the ~35us we control.
//
// Index algebra (verified rounds 1-10):
//  x1[b,i,k] = conv1_flat[b][i*32+k]   (raw reshape; conv1 [ch][hw] buffer IS x1 flat)
//  x2[b,k,j] = conv2 natural [k][j]
//  y3[b,j,c] = conv3_flat[b][j*32+c]
//  attn[b,i,j] = sum_k x1*x2 ; softmax over BATCH axis (4 elems, per (i,j))
//  O[b,i,c] = sum_j attn*y3 ;  y2[b,ch,hw] = O_flat[b][ch*4096+hw] -> conv4
//
// MFMA f16 16x16x32 (HW-verified r2-r10):
//  A: A[m=lane&15][k=(lane>>4)*8+e]   B: B[k=(lane>>4)*8+e][n=lane&15]
//  C/D: row=(lane>>4)*4+reg, col=lane&15;  A-frag of M == B-frag of M^T.
// Stage 1 computes S^T with PERMUTED X2 rows (tile jh row m' -> j=(m'>>2)*8+(m'&3)+jh*4)
// so lane (q,m) ends holding exactly P[i=m][k=q*8+e] = stage-2 B-frag. No transpose.
// X2f/Y3f fragment-order buffers -> attn loads are lane*16B contiguous:
//  X2f h8-index: ((b*128 + jt)*2 + jh)*64 + lane  (value: x2[b][k=q*8+e][jt*32+perm(m,jh)])
//  Y3f h8-index: ((b*128 + jt)*2 + ch)*64 + lane  (value: y3[b][jt*32+q*8+e][ch*16+m])
// X1 carries log2e so softmax is raw exp2 (|s*log2e| < ~50, safe in f32).
//
// ws: X1h 1MB @0 | X2f 1MB @1M | Y3f 1MB @2M | OPh 16MB @3M | O(f32) 4MB @19M

typedef _Float16 half8 __attribute__((ext_vector_type(8)));
typedef _Float16 half4 __attribute__((ext_vector_type(4)));
typedef float f32x4 __attribute__((ext_vector_type(4)));

#define N_PIX 4096
#define NB    4
#define JS    16
#define LOG2E 1.44269504088896f

// grid (256, 3): bx = b(2b) | chunk(4b, 256 hw) | og(2b, 8 o).  LDS weights.
__global__ __launch_bounds__(256) void convs_kernel(
    const float* __restrict__ x,
    const float* __restrict__ w1, const float* __restrict__ b1,
    const float* __restrict__ w2, const float* __restrict__ b2,
    const float* __restrict__ w3, const float* __restrict__ b3,
    _Float16* __restrict__ X1h, _Float16* __restrict__ X2f, _Float16* __restrict__ Y3f)
{
    const int t = blockIdx.y;
    const float* __restrict__ w  = (t == 0) ? w1 : ((t == 1) ? w2 : w3);
    const float* __restrict__ bb = (t == 0) ? b1 : ((t == 1) ? b2 : b3);

    __shared__ float sw[8][64];            // this block's 8 o rows (2 KB)
    __shared__ float sbias[8];
    __shared__ _Float16 sbuf[2048];        // union: t1 [256 j][8 k] | t2 [8 o][32 c][8 jl]

    const int tid   = threadIdx.x;
    const int b     = blockIdx.x >> 6;
    const int chunk = (blockIdx.x >> 2) & 15;
    const int og    = blockIdx.x & 3;
    const int o0    = og * 8;
    const int hw    = chunk * 256 + tid;

    for (int e = tid; e < 8 * 64; e += 256)
        sw[e >> 6][e & 63] = w[(o0 + (e >> 6)) * 64 + (e & 63)];
    if (tid < 8) sbias[tid] = bb[o0 + tid];
    __syncthreads();

    float xi[64];
    const float* xb = x + b * 64 * N_PIX + hw;
    #pragma unroll
    for (int c = 0; c < 64; c++) xi[c] = xb[c * N_PIX];

    float acc[8];
    #pragma unroll
    for (int oo = 0; oo < 8; oo++) {
        float a0 = sbias[oo], a1 = 0.f, a2 = 0.f, a3 = 0.f;
        #pragma unroll
        for (int c = 0; c < 64; c += 4) {
            a0 += xi[c + 0] * sw[oo][c + 0];
            a1 += xi[c + 1] * sw[oo][c + 1];
            a2 += xi[c + 2] * sw[oo][c + 2];
            a3 += xi[c + 3] * sw[oo][c + 3];
        }
        acc[oo] = (a0 + a1) + (a2 + a3);
    }

    if (t == 0) {
        // X1h flat [o][hw] (== x1 flat [i*32+k]); fold log2e for exp2 softmax
        #pragma unroll
        for (int oo = 0; oo < 8; oo++)
            X1h[b * 131072 + (o0 + oo) * N_PIX + hw] = (_Float16)(acc[oo] * LOG2E);
    } else if (t == 1) {
        // block's k-range o0..o0+7 = exactly q=og octet of the frag; sbuf[j_loc][e]
        #pragma unroll
        for (int oo = 0; oo < 8; oo++)
            sbuf[tid * 8 + oo] = (_Float16)acc[oo];
        __syncthreads();
        const int m    = tid & 15;
        const int jh   = (tid >> 4) & 1;
        const int jt_l = (tid >> 5) & 7;                   // 8 j-tiles per 256 hw
        const int jl   = jt_l * 32 + ((m >> 2) * 8) + (m & 3) + jh * 4;  // perm row
        half8 v = *(half8*)&sbuf[jl * 8];
        *(half8*)&X2f[(((b * 128 + chunk * 8 + jt_l) * 2 + jh) * 64 + og * 16 + m) * 8] = v;
    } else {
        // y3 elem acc[oo]: o = o0+oo, j = o*128 + (hw>>5), c = hw&31.
        // jt = (o0+oo)*4 + (chunk>>2); within-tile j&31: q = chunk&3, e = jl.
        const int c  = tid & 31;
        const int jl = tid >> 5;                           // 0..7
        #pragma unroll
        for (int oo = 0; oo < 8; oo++)
            sbuf[(oo * 32 + c) * 8 + jl] = (_Float16)acc[oo];
        __syncthreads();
        const int m  = tid & 15;
        const int ch = (tid >> 4) & 1;
        const int oo = (tid >> 5) & 7;
        half8 v = *(half8*)&sbuf[(oo * 32 + ch * 16 + m) * 8];
        const int jt = (o0 + oo) * 4 + (chunk >> 2);
        *(half8*)&Y3f[(((b * 128 + jt) * 2 + ch) * 64 + (chunk & 3) * 16 + m) * 8] = v;
    }
}

// grid (256, 16): bx = i-tile (16 rows), by = js. Wave wv: 2 jt tiles (64 j).
__global__ __launch_bounds__(256) void attn_kernel(
    const _Float16* __restrict__ X1h, const _Float16* __restrict__ X2f,
    const _Float16* __restrict__ Y3f, _Float16* __restrict__ OPh)
{
    __shared__ _Float16 sRedH[4 * 64 * 36];  // 18.4 KB; stride 36 keeps half4 8B-aligned

    const int tid  = threadIdx.x;
    const int wv   = tid >> 6;
    const int lane = tid & 63;
    const int m    = lane & 15;
    const int q    = lane >> 4;
    const int i0   = blockIdx.x * 16;
    const int js   = blockIdx.y;
    const int jt0  = js * 8 + wv * 2;

    // stage-1 B-frags (x1 A-frag data), all batches (1 KB contiguous per wave-load)
    half8 bx1[NB];
    #pragma unroll
    for (int b = 0; b < NB; b++)
        bx1[b] = *(const half8*)&X1h[b * 131072 + (i0 + m) * 32 + q * 8];

    f32x4 oaccT[NB][2];                      // [b][ch], lane holds O^T[c][i]
    #pragma unroll
    for (int b = 0; b < NB; b++) {
        oaccT[b][0] = (f32x4){0.f, 0.f, 0.f, 0.f};
        oaccT[b][1] = (f32x4){0.f, 0.f, 0.f, 0.f};
    }

    #pragma unroll
    for (int jt = 0; jt < 2; jt++) {         // fully unrolled: 2 independent chains
        const int jg = jt0 + jt;

        // fully-coalesced fragment loads (lane*16B contiguous, 1 KB per wave-inst)
        half8 ax2[NB][2], ay3[NB][2];
        #pragma unroll
        for (int b = 0; b < NB; b++) {
            #pragma unroll
            for (int jh = 0; jh < 2; jh++)
                ax2[b][jh] = *(const half8*)&X2f[(((b * 128 + jg) * 2 + jh) * 64 + lane) * 8];
            #pragma unroll
            for (int ch = 0; ch < 2; ch++)
                ay3[b][ch] = *(const half8*)&Y3f[(((b * 128 + jg) * 2 + ch) * 64 + lane) * 8];
        }

        // stage 1: S^T (logits pre-scaled by log2e)
        f32x4 sT[NB][2];
        #pragma unroll
        for (int b = 0; b < NB; b++)
            #pragma unroll
            for (int jh = 0; jh < 2; jh++)
                sT[b][jh] = __builtin_amdgcn_mfma_f32_16x16x32_f16(
                    ax2[b][jh], bx1[b], (f32x4){0.f, 0.f, 0.f, 0.f}, 0, 0, 0);

        // batch-softmax via raw exp2, pack stage-2 B-frag in-lane
        half8 pf[NB];
        #pragma unroll
        for (int jh = 0; jh < 2; jh++)
            #pragma unroll
            for (int r = 0; r < 4; r++) {
                float e0 = exp2f(sT[0][jh][r]);
                float e1 = exp2f(sT[1][jh][r]);
                float e2 = exp2f(sT[2][jh][r]);
                float e3 = exp2f(sT[3][jh][r]);
                float rs = __builtin_amdgcn_rcpf(e0 + e1 + e2 + e3);
                pf[0][jh * 4 + r] = (_Float16)(e0 * rs);
                pf[1][jh * 4 + r] = (_Float16)(e1 * rs);
                pf[2][jh * 4 + r] = (_Float16)(e2 * rs);
                pf[3][jh * 4 + r] = (_Float16)(e3 * rs);
            }

        // stage 2: O^T += Y3^T x P^T
        #pragma unroll
        for (int b = 0; b < NB; b++)
            #pragma unroll
            for (int ch = 0; ch < 2; ch++)
                oaccT[b][ch] = __builtin_amdgcn_mfma_f32_16x16x32_f16(
                    ay3[b][ch], pf[b], oaccT[b][ch], 0, 0, 0);
    }

    // cross-wave reduction in f16 LDS (partials are attn-weighted, |v| small)
    #pragma unroll
    for (int b = 0; b < NB; b++)
        #pragma unroll
        for (int ch = 0; ch < 2; ch++) {
            half4 h;
            #pragma unroll
            for (int r = 0; r < 4; r++) h[r] = (_Float16)oaccT[b][ch][r];
            *(half4*)&sRedH[(wv * 64 + lane) * 36 + b * 8 + ch * 4] = h;
        }
    __syncthreads();

    const int bb = tid >> 6;                 // wave writes batch b=bb
    const int lp = tid & 63;
    const int mm = lp & 15;
    const int qq = lp >> 4;
    #pragma unroll
    for (int ch = 0; ch < 2; ch++) {
        half4 h0 = *(half4*)&sRedH[(0 * 64 + lp) * 36 + bb * 8 + ch * 4];
        half4 h1 = *(half4*)&sRedH[(1 * 64 + lp) * 36 + bb * 8 + ch * 4];
        half4 h2 = *(half4*)&sRedH[(2 * 64 + lp) * 36 + bb * 8 + ch * 4];
        half4 h3 = *(half4*)&sRedH[(3 * 64 + lp) * 36 + bb * 8 + ch * 4];
        half4 v;
        #pragma unroll
        for (int r = 0; r < 4; r++)
            v[r] = (_Float16)(((float)h0[r] + (float)h1[r]) + ((float)h2[r] + (float)h3[r]));
        *(half4*)&OPh[js * 524288 + (bb * 4096 + i0 + mm) * 32 + ch * 16 + qq * 4] = v;
    }
}

// grid 512: sum 16 f16 partial slices -> f32 O.  half4/thread (2 blocks/CU).
__global__ __launch_bounds__(256) void reduce_kernel(
    const _Float16* __restrict__ OPh, float* __restrict__ O)
{
    const int u = blockIdx.x * 256 + threadIdx.x;    // 0..131071
    const int base = u * 4;
    float acc[4] = {};
    #pragma unroll
    for (int p = 0; p < JS; p++) {
        half4 v = *(const half4*)&OPh[p * 524288 + base];
        #pragma unroll
        for (int e = 0; e < 4; e++) acc[e] += (float)v[e];
    }
    *(f32x4*)&O[base] = (f32x4){acc[0], acc[1], acc[2], acc[3]};
}

// grid (256, 4): bx = b(2b) | chunk(6b, 64 hw); by*16 + og*4 = o-range (4 o / thread).
__global__ __launch_bounds__(256) void out_kernel(
    const float* __restrict__ O, const float* __restrict__ w4,
    const float* __restrict__ b4, float* __restrict__ out)
{
    __shared__ float sw[16][32];             // this by's 16 o rows (2 KB)
    __shared__ float sbias[16];
    const int tid = threadIdx.x;
    const int ob  = blockIdx.y * 16;
    for (int e = tid; e < 16 * 32; e += 256)
        sw[e >> 5][e & 31] = w4[(ob + (e >> 5)) * 32 + (e & 31)];
    if (tid < 16) sbias[tid] = b4[ob + tid];
    __syncthreads();

    const int b   = blockIdx.x >> 6;
    const int hw  = (blockIdx.x & 63) * 64 + (tid & 63);
    const int og  = tid >> 6;                // 0..3 -> 4-o quarters

    float y2[32];
    #pragma unroll
    for (int ch = 0; ch < 32; ch++)
        y2[ch] = O[b * 131072 + ch * 4096 + hw];       // 32 independent coalesced loads

    float* obp = out + b * 64 * N_PIX + hw;
    #pragma unroll
    for (int oo = 0; oo < 4; oo++) {
        const int ol = og * 4 + oo;
        float a0 = sbias[ol], a1 = 0.f, a2 = 0.f, a3 = 0.f;
        #pragma unroll
        for (int c = 0; c < 32; c += 4) {
            a0 += y2[c + 0] * sw[ol][c + 0];
            a1 += y2[c + 1] * sw[ol][c + 1];
            a2 += y2[c + 2] * sw[ol][c + 2];
            a3 += y2[c + 3] * sw[ol][c + 3];
        }
        obp[(ob + ol) * N_PIX] = (a0 + a1) + (a2 + a3);
    }
}

extern "C" void kernel_launch(void* const* d_in, const int* in_sizes, int n_in,
                              void* d_out, int out_size, void* d_ws, size_t ws_size,
                              hipStream_t stream) {
    const float* x  = (const float*)d_in[0];
    const float* w1 = (const float*)d_in[1];
    const float* b1 = (const float*)d_in[2];
    const float* w2 = (const float*)d_in[3];
    const float* b2 = (const float*)d_in[4];
    const float* w3 = (const float*)d_in[5];
    const float* b3 = (const float*)d_in[6];
    const float* w4 = (const float*)d_in[7];
    const float* b4 = (const float*)d_in[8];

    char* wsb = (char*)d_ws;
    _Float16* X1h = (_Float16*)(wsb);
    _Float16* X2f = (_Float16*)(wsb + (1 << 20));
    _Float16* Y3f = (_Float16*)(wsb + (2 << 20));
    _Float16* OPh = (_Float16*)(wsb + (3 << 20));    // JS x 1MB f16 = 16 MB
    float*    O   = (float*)   (wsb + (19 << 20));   // 4MB f32
    float*    out = (float*)d_out;

    dim3 g1(256, 3);
    convs_kernel<<<g1, 256, 0, stream>>>(x, w1, b1, w2, b2, w3, b3, X1h, X2f, Y3f);
    dim3 g2(256, JS);
    attn_kernel<<<g2, 256, 0, stream>>>(X1h, X2f, Y3f, OPh);
    reduce_kernel<<<512, 256, 0, stream>>>(OPh, O);
    dim3 g4(256, 4);
    out_kernel<<<g4, 256, 0, stream>>>(O, w4, b4, out);
}